// Round 3
// baseline (407.796 us; speedup 1.0000x reference)
//
#include <hip/hip_runtime.h>

#define NB 4
#define NC 512
#define NT 4096
#define NTILE 528   // 32*33/2 triangular 128x128 tiles per batch

typedef __attribute__((ext_vector_type(4))) float f32x4;
typedef __attribute__((ext_vector_type(8))) short short8;

typedef const __attribute__((address_space(1))) unsigned int* gp1_t;
typedef __attribute__((address_space(3))) unsigned int* lp3_t;

__device__ __forceinline__ void gload16(const short* g, short* l) {
  // async global->LDS, 16B/lane; LDS dest = wave-uniform base + lane*16
  __builtin_amdgcn_global_load_lds((gp1_t)g, (lp3_t)l, 16, 0, 0);
}

// Raw barrier / waitcnt with memory clobbers: keeps the compiler from
// draining vmcnt(0) at every barrier. Each wave issues 4 DMAs per k-step;
// vmcnt(4*D) = the oldest step's 4 have landed (D = steps still in flight).
#define BARRIER()  asm volatile("s_barrier" ::: "memory")
#define WAITVM0()  asm volatile("s_waitcnt vmcnt(0)" ::: "memory")
#define WAITVM4()  asm volatile("s_waitcnt vmcnt(4)" ::: "memory")
#define WAITVM8()  asm volatile("s_waitcnt vmcnt(8)" ::: "memory")
#define WAITVM12() asm volatile("s_waitcnt vmcnt(12)" ::: "memory")
#define WAITVM16() asm volatile("s_waitcnt vmcnt(16)" ::: "memory")

__device__ __forceinline__ short f2bf(float f) {
  union { float f; unsigned u; } v; v.f = f;
  unsigned r = v.u + 0x7fffu + ((v.u >> 16) & 1u);
  return (short)(r >> 16);
}
__device__ __forceinline__ float bf2f(short s) {
  union { unsigned u; float f; } v; v.u = ((unsigned)(unsigned short)s) << 16;
  return v.f;
}

// ---------------------------------------------------------------------------
// LDS XOR swizzle (T2): buffers are 64 rows x 32 shorts (64 B rows). Unswizzled
// fragment reads put a quarter-wave's 16 lanes (16 different rows, same 16B
// column-group) on 2 four-bank slots -> 8-way conflict. Store column-group
// cg at cg ^ s(row), s(row) = (row>>1)&3. With global_load_lds the LDS dest
// stays linear; swizzle via per-lane GLOBAL source column (rule 21) + read
// column. Both collapse to per-thread constants. Verified round 2:
// SQ_LDS_BANK_CONFLICT 4.33M -> 0.
// ---------------------------------------------------------------------------
#define SCOL_SWZ(lane) ((((lane) & 3) ^ (((lane) >> 3) & 3)) * 8)
#define FKO_SWZ(lane)  (((((lane) >> 4) ^ (((lane) >> 1) & 3)) & 3) * 8)

// ---------------------------------------------------------------------------
// Multi-buffered NT-GEMM core, prefetch depth NBUF-1: D[m,n] += sum_k A[m,k]*B[n,k]
// 128x128 tile, BK=32, 4 waves, 4x4 of 16x16x32 bf16 MFMAs per wave.
// lds: NBUF*8192 shorts, buffer b at lds + b*8192 (A 4096 + B 4096).
// NBUF=2 (32 KB): 5 blocks/CU residency for short-loop L2-resident GEMMs.
// NBUF=5 (80 KB): grid-512 kernels (2 blocks/CU regardless), deep prefetch.
// ---------------------------------------------------------------------------
template <int NBUF>
__device__ __forceinline__ void gemm_tile(const short* __restrict__ A, int lda,
                                          const short* __restrict__ Bg, int ldb,
                                          int m0, int n0, int ksteps,
                                          f32x4 (&acc)[4][4], short* lds) {
  const int tid  = threadIdx.x;
  const int lane = tid & 63;
  const int wv   = tid >> 6;
  const int wm = (wv >> 1) * 64;
  const int wn = (wv & 1) * 64;
  const int srow = wv * 16 + (lane >> 2);   // staging row, 0..63 (+64 issue 1)
  const int scol = SCOL_SWZ(lane);          // swizzled staging col (shorts)
  const int fm  = lane & 15;                // fragment row
  const int fko = FKO_SWZ(lane);            // swizzled fragment k offset

  const short* Ap0 = A  + (size_t)(m0 + srow) * lda + scol;
  const short* Ap1 = Ap0 + (size_t)64 * lda;
  const short* Bp0 = Bg + (size_t)(n0 + srow) * ldb + scol;
  const short* Bp1 = Bp0 + (size_t)64 * ldb;

  auto issue = [&](int kt) {
    short* base = lds + (kt % NBUF) * 8192;
    const int k0 = kt * 32;
    gload16(Ap0 + k0, base + wv * 512);
    gload16(Ap1 + k0, base + 2048 + wv * 512);
    gload16(Bp0 + k0, base + 4096 + wv * 512);
    gload16(Bp1 + k0, base + 6144 + wv * 512);
  };

  issue(0);
#pragma unroll
  for (int p = 1; p < NBUF - 1; ++p)
    if (p < ksteps) issue(p);

  for (int kt = 0; kt < ksteps; ++kt) {
    const short* As = lds + (kt % NBUF) * 8192;
    const short* Bs = As + 4096;
    if (kt) BARRIER();                      // prior readers of reused buf done
    if constexpr (NBUF == 5) {
      if (kt + 4 < ksteps)      { issue(kt + 4); WAITVM16(); }
      else if (kt + 3 < ksteps) { WAITVM12(); }
      else if (kt + 2 < ksteps) { WAITVM8(); }
      else if (kt + 1 < ksteps) { WAITVM4(); }
      else                      { WAITVM0(); }
    } else if constexpr (NBUF == 3) {
      if (kt + 2 < ksteps)      { issue(kt + 2); WAITVM8(); }
      else if (kt + 1 < ksteps) { WAITVM4(); }
      else                      { WAITVM0(); }
    } else {  // NBUF == 2, depth-1
      if (kt + 1 < ksteps)      { issue(kt + 1); WAITVM4(); }
      else                      { WAITVM0(); }
    }
    BARRIER();                              // all waves' step-kt DMAs landed
    short8 af[4], bfr[4];
#pragma unroll
    for (int i = 0; i < 4; ++i)
      af[i] = *(const short8*)(As + (wm + i * 16 + fm) * 32 + fko);
#pragma unroll
    for (int j = 0; j < 4; ++j)
      bfr[j] = *(const short8*)(Bs + (wn + j * 16 + fm) * 32 + fko);
#pragma unroll
    for (int i = 0; i < 4; ++i)
#pragma unroll
      for (int j = 0; j < 4; ++j)
        acc[i][j] = __builtin_amdgcn_mfma_f32_16x16x32_bf16(af[i], bfr[j], acc[i][j], 0, 0, 0);
  }
}

#define ACC_INIT                                  \
  f32x4 acc[4][4];                                \
  {                                               \
    const f32x4 z = {0.f, 0.f, 0.f, 0.f};         \
    for (int i = 0; i < 4; ++i)                   \
      for (int j = 0; j < 4; ++j) acc[i][j] = z;  \
  }

#define EPI_IDX                                   \
  const int lane = threadIdx.x & 63;              \
  const int wave = threadIdx.x >> 6;              \
  const int wm = (wave >> 1) * 64;                \
  const int wn = (wave & 1) * 64;

#define GEMM_LDS2 __shared__ short lds[16384];    // 2 bufs, 32 KB -> 5 blocks/CU
#define GEMM_LDS5 __shared__ short lds[40960];    // 5 bufs, 80 KB

// ---------------------------------------------------------------------------
// XCD-locality swizzle for flat grids of (row-stripe, 4 col-chunks):
// dispatch round-robins blockIdx.x%8 across XCDs; decode so each XCD sees 4
// consecutive col-chunks of the same row-stripe. rows descend (long first).
// ---------------------------------------------------------------------------
__device__ __forceinline__ void xcd_rowchunk(int x, int nrows, int& row, int& chunk) {
  const int xcd  = x & 7;
  const int slot = x >> 3;
  row   = nrows - 1 - (xcd + 8 * (slot >> 2));
  chunk = slot & 3;
}

// ---------------------------------------------------------------------------
// Work-balanced row map for k_pv (triangular: ksteps = 4*(bm+1)).
// Each XCD x owns rows {31-x, 23-x, 8+x, x}; reversing order for z>=2 pairs
// long rows with short on the same CU -> every CU = 132 ksteps exactly.
// (Round-2 verified: k_pv dropped out of the top-5 dispatches.)
// ---------------------------------------------------------------------------
__device__ __forceinline__ void pv_rowchunk(int x, int z, int& bm, int& chunk) {
  const int xcd  = x & 7;
  const int slot = x >> 3;           // 0..15
  int ridx = slot >> 2;              // 0..3
  if (z >= 2) ridx = 3 - ridx;
  bm = (ridx == 0) ? (31 - xcd)
     : (ridx == 1) ? (23 - xcd)
     : (ridx == 2) ? (8 + xcd)
                   : xcd;
  chunk = slot & 3;
}

// ---------------------------------------------------------------------------
// x [B,C,T] f32 -> xT [B,T,C] bf16 (tiled transpose through LDS)
// ---------------------------------------------------------------------------
__global__ __launch_bounds__(256) void k_transpose(const float* __restrict__ x,
                                                   short* __restrict__ xT) {
  __shared__ float tile[32][33];
  const int b  = blockIdx.z;
  const int t0 = blockIdx.x * 32;
  const int c0 = blockIdx.y * 32;
  const int tx = threadIdx.x & 31;
  const int ty = threadIdx.x >> 5;
  const float* xp = x + ((size_t)b * NC + c0) * NT + t0;
#pragma unroll
  for (int i = 0; i < 32; i += 8)
    tile[ty + i][tx] = xp[(size_t)(ty + i) * NT + tx];
  __syncthreads();
  short* op = xT + ((size_t)b * NT + t0) * NC + c0;
#pragma unroll
  for (int i = 0; i < 32; i += 8)
    op[(size_t)(ty + i) * NC + tx] = f2bf(tile[tx][ty + i]);
}

// f32 -> bf16 conversion of all 4 weight matrices in one launch
__global__ __launch_bounds__(256) void k_wcvt(const float* __restrict__ s0, const float* __restrict__ s1,
                                              const float* __restrict__ s2, const float* __restrict__ s3,
                                              short* __restrict__ d0, short* __restrict__ d1,
                                              short* __restrict__ d2, short* __restrict__ d3) {
  const float* s; short* d;
  switch (blockIdx.y) {
    case 0: s = s0; d = d0; break;
    case 1: s = s1; d = d1; break;
    case 2: s = s2; d = d2; break;
    default: s = s3; d = d3; break;
  }
  const int i = (blockIdx.x * 256 + threadIdx.x) * 4;
  const float4 v = *(const float4*)(s + i);
  short4 o;
  o.x = f2bf(v.x); o.y = f2bf(v.y); o.z = f2bf(v.z); o.w = f2bf(v.w);
  *(short4*)(d + i) = o;
}

// ---------------------------------------------------------------------------
// Fused Q/K/V projections, one launch. blockIdx.y selects:
//   y=0: Q[t,o] = xT·Wq^T + bq   -> bf16 [T,C]
//   y=1: K[t,o] = xT·Wk^T + bk   -> bf16 [T,C]
//   y=2: VT[o,t] = Wv·xT^T + bv  -> bf16 [C,T]
// NBUF=2 / 32 KB LDS: 5 blocks/CU so epilogues overlap other blocks' GEMMs.
// ---------------------------------------------------------------------------
__global__ __launch_bounds__(256, 5) void k_qkv(const short* __restrict__ xT,
                                                const short* __restrict__ Wq,
                                                const float* __restrict__ bq,
                                                const short* __restrict__ Wk,
                                                const float* __restrict__ bk,
                                                const short* __restrict__ Wv,
                                                const float* __restrict__ bv,
                                                short* __restrict__ Q,
                                                short* __restrict__ K,
                                                short* __restrict__ VT) {
  GEMM_LDS2;
  const int b = blockIdx.z;
  const int y = blockIdx.y;
  int row, chunk;
  xcd_rowchunk((int)blockIdx.x, NT / 128, row, chunk);
  const short* Xb = xT + (size_t)b * NT * NC;
  ACC_INIT;
  if (y < 2) {
    const short* W = (y == 0) ? Wq : Wk;
    const float* bias = (y == 0) ? bq : bk;
    short* O = ((y == 0) ? Q : K) + (size_t)b * NT * NC;
    const int m0 = row * 128;
    const int n0 = chunk * 128;
    gemm_tile<2>(Xb, NC, W, NC, m0, n0, NC / 32, acc, lds);
    EPI_IDX;
#pragma unroll
    for (int j = 0; j < 4; ++j) {
      const int n = n0 + wn + j * 16 + (lane & 15);
      const float bv_ = bias[n];
#pragma unroll
      for (int i = 0; i < 4; ++i) {
        const int mb = m0 + wm + i * 16 + ((lane >> 4) * 4);
#pragma unroll
        for (int r = 0; r < 4; ++r)
          O[(size_t)(mb + r) * NC + n] = f2bf(acc[i][j][r] + bv_);
      }
    }
  } else {
    const int n0 = row * 128;    // xT row-stripe (B operand)
    const int m0 = chunk * 128;  // Wv row chunk
    gemm_tile<2>(Wv, NC, Xb, NC, m0, n0, NC / 32, acc, lds);
    EPI_IDX;
    short* O = VT + (size_t)b * NC * NT;
#pragma unroll
    for (int j = 0; j < 4; ++j) {
      const int n = n0 + wn + j * 16 + (lane & 15);
#pragma unroll
      for (int i = 0; i < 4; ++i) {
        const int mb = m0 + wm + i * 16 + ((lane >> 4) * 4);
#pragma unroll
        for (int r = 0; r < 4; ++r)
          O[(size_t)(mb + r) * NT + n] = f2bf(acc[i][j][r] + bv[mb + r]);
      }
    }
  }
}

// ---------------------------------------------------------------------------
// Scores + softmax numerator into TRIANGULAR-PACKED tile layout.
// XCD-locality: 8x8-tile supertile decomposition; block x -> (xcd=x&7,
// slot=x>>3) gives each XCD a contiguous 66-tile range (~2 MB working set).
// P = exp(scale*q.k) for s<=t else 0, contiguous 128x128 bf16 tile.
// NBUF=2 / 32 KB LDS: 5 blocks/CU (was 3) -- the heavy exp/store epilogue of
// one block now overlaps the GEMM loops of four others.
// Epilogue VALU diet: exp2f with folded scale*log2e constant (1 mul + 1 exp
// per elem) and paired v_cvt_pk_bf16_f32 (RNE, same as manual f2bf).
// ---------------------------------------------------------------------------
__global__ __launch_bounds__(256, 5) void k_scores(const short* __restrict__ Q,
                                                   const short* __restrict__ K,
                                                   short* __restrict__ P,
                                                   float* __restrict__ Lrow) {
  // supertile-ordered position, contiguous per XCD
  const int p = (((int)blockIdx.x & 7) * 66) + ((int)blockIdx.x >> 3);
  int bm = 0, bn = 0;
  {
    int base = 0;
    for (int sr = 0; sr < 4; ++sr) {
      bool done = false;
      for (int sc = 0; sc <= sr; ++sc) {
        const int sz = (sc == sr) ? 36 : 64;
        if (p < base + sz) {
          const int q = p - base;
          int i, j;
          if (sc == sr) {
            i = 0;
            while ((i + 1) * (i + 2) / 2 <= q) ++i;
            j = q - i * (i + 1) / 2;
          } else { i = q >> 3; j = q & 7; }
          bm = sr * 8 + i; bn = sc * 8 + j;
          done = true; break;
        }
        base += sz;
      }
      if (done) break;
    }
  }
  GEMM_LDS2;
  const int b  = blockIdx.z;
  const int m0 = bm * 128;
  const int n0 = bn * 128;
  ACC_INIT;
  gemm_tile<2>(Q + (size_t)b * NT * NC, NC, K + (size_t)b * NT * NC, NC,
               m0, n0, NC / 32, acc, lds);
  EPI_IDX;
  const float kls = 0.06376070265f;          // 512^-0.5 * log2(e)
  const int idx = bm * (bm + 1) / 2 + bn;    // storage order unchanged
  short* Tp = P + ((size_t)b * NTILE + (size_t)idx) * 16384;
  float* Lp = Lrow + (size_t)b * NT;
  float psum[4][4];
#pragma unroll
  for (int i = 0; i < 4; ++i)
#pragma unroll
    for (int r = 0; r < 4; ++r) psum[i][r] = 0.f;

  if (bn < bm) {
    // interior: causal mask always true -- branchless, packed bf16 convert
#pragma unroll
    for (int j = 0; j < 4; ++j) {
      const int ln = wn + j * 16 + (lane & 15);
#pragma unroll
      for (int i = 0; i < 4; ++i) {
        const int lmb = wm + i * 16 + ((lane >> 4) * 4);
        const float e0 = exp2f(acc[i][j][0] * kls);
        const float e1 = exp2f(acc[i][j][1] * kls);
        const float e2 = exp2f(acc[i][j][2] * kls);
        const float e3 = exp2f(acc[i][j][3] * kls);
        unsigned pk01, pk23;
        asm("v_cvt_pk_bf16_f32 %0, %1, %2" : "=v"(pk01) : "v"(e0), "v"(e1));
        asm("v_cvt_pk_bf16_f32 %0, %1, %2" : "=v"(pk23) : "v"(e2), "v"(e3));
        Tp[(lmb + 0) * 128 + ln] = (short)(pk01 & 0xffffu);
        Tp[(lmb + 1) * 128 + ln] = (short)(pk01 >> 16);
        Tp[(lmb + 2) * 128 + ln] = (short)(pk23 & 0xffffu);
        Tp[(lmb + 3) * 128 + ln] = (short)(pk23 >> 16);
        // L accumulates exactly the rounded values P stores
        union { unsigned u; float f; } c0, c1, c2, c3;
        c0.u = pk01 << 16; c1.u = pk01 & 0xffff0000u;
        c2.u = pk23 << 16; c3.u = pk23 & 0xffff0000u;
        psum[i][0] += c0.f; psum[i][1] += c1.f;
        psum[i][2] += c2.f; psum[i][3] += c3.f;
      }
    }
  } else {
    // diagonal tile: evaluate mask per element
#pragma unroll
    for (int j = 0; j < 4; ++j) {
      const int ln = wn + j * 16 + (lane & 15);
      const int n  = n0 + ln;
#pragma unroll
      for (int i = 0; i < 4; ++i) {
        const int lmb = wm + i * 16 + ((lane >> 4) * 4);
#pragma unroll
        for (int r = 0; r < 4; ++r) {
          const int m = m0 + lmb + r;
          float pr = 0.f;
          short pb = 0;
          if (n <= m) {
            pb = f2bf(exp2f(acc[i][j][r] * kls));
            pr = bf2f(pb);
          }
          Tp[(lmb + r) * 128 + ln] = pb;
          psum[i][r] += pr;
        }
      }
    }
  }
#pragma unroll
  for (int i = 0; i < 4; ++i)
#pragma unroll
    for (int r = 0; r < 4; ++r) {
      float v = psum[i][r];
      v += __shfl_xor(v, 1);
      v += __shfl_xor(v, 2);
      v += __shfl_xor(v, 4);
      v += __shfl_xor(v, 8);
      if ((lane & 15) == 0) {
        const int m = m0 + wm + i * 16 + ((lane >> 4) * 4) + r;
        atomicAdd(&Lp[m], v);
      }
    }
}

// ---------------------------------------------------------------------------
// PV: H[t,c] = (1/L[t]) * sum_{s<=t} P[t,s] * VT[c,s]  -> bf16 [T,C]
// flat grid (128, 1, B): XCD-grouped, work-balanced row map (see pv_rowchunk).
// Depth-4 prefetch (5 LDS buffers, 80 KB): 2 blocks/CU either way.
// ---------------------------------------------------------------------------
__global__ __launch_bounds__(256, 2) void k_pv(const short* __restrict__ P,
                                               const short* __restrict__ VT,
                                               const float* __restrict__ Lr,
                                               short* __restrict__ H) {
  GEMM_LDS5;
  const int b = blockIdx.z;
  int bm, chunk;
  pv_rowchunk((int)blockIdx.x, b, bm, chunk);
  const int m0 = bm * 128;
  const int n0 = chunk * 128;
  const int ksteps = (bm + 1) * 4;

  const short* Ptri = P + ((size_t)b * NTILE + (size_t)bm * (bm + 1) / 2) * 16384;
  const short* Bg   = VT + (size_t)b * NC * NT;

  ACC_INIT;
  const int tid  = threadIdx.x;
  const int lane = tid & 63;
  const int wv   = tid >> 6;
  const int wm = (wv >> 1) * 64;
  const int wn = (wv & 1) * 64;
  const int srow = wv * 16 + (lane >> 2);
  const int scol = SCOL_SWZ(lane);
  const int fm  = lane & 15;
  const int fko = FKO_SWZ(lane);

  const short* Bp0 = Bg + (size_t)(n0 + srow) * NT + scol;
  const short* Bp1 = Bp0 + (size_t)64 * NT;

  auto issue = [&](int kt) {
    short* base = lds + (kt % 5) * 8192;
    const short* At = Ptri + (size_t)(kt >> 2) * 16384 + (kt & 3) * 32;
    const short* Ap0 = At + srow * 128 + scol;
    const int k0 = kt * 32;
    gload16(Ap0, base + wv * 512);
    gload16(Ap0 + 64 * 128, base + 2048 + wv * 512);
    gload16(Bp0 + k0, base + 4096 + wv * 512);
    gload16(Bp1 + k0, base + 6144 + wv * 512);
  };

  issue(0);
#pragma unroll
  for (int p = 1; p < 4; ++p)
    if (p < ksteps) issue(p);
  for (int kt = 0; kt < ksteps; ++kt) {
    const short* As = lds + (kt % 5) * 8192;
    const short* Bs = As + 4096;
    if (kt) BARRIER();
    if (kt + 4 < ksteps)      { issue(kt + 4); WAITVM16(); }
    else if (kt + 3 < ksteps) { WAITVM12(); }
    else if (kt + 2 < ksteps) { WAITVM8(); }
    else if (kt + 1 < ksteps) { WAITVM4(); }
    else                      { WAITVM0(); }
    BARRIER();
    short8 af[4], bfr[4];
#pragma unroll
    for (int i = 0; i < 4; ++i)
      af[i] = *(const short8*)(As + (wm + i * 16 + fm) * 32 + fko);
#pragma unroll
    for (int j = 0; j < 4; ++j)
      bfr[j] = *(const short8*)(Bs + (wn + j * 16 + fm) * 32 + fko);
#pragma unroll
    for (int i = 0; i < 4; ++i)
#pragma unroll
      for (int j = 0; j < 4; ++j)
        acc[i][j] = __builtin_amdgcn_mfma_f32_16x16x32_bf16(af[i], bfr[j], acc[i][j], 0, 0, 0);
  }

  const float* L = Lr + (size_t)b * NT;
  short* Hp = H + (size_t)b * NT * NC;
#pragma unroll
  for (int i = 0; i < 4; ++i) {
    const int mb = m0 + wm + i * 16 + ((lane >> 4) * 4);
    float rinv[4];
#pragma unroll
    for (int r = 0; r < 4; ++r) rinv[r] = 1.f / L[mb + r];
#pragma unroll
    for (int j = 0; j < 4; ++j) {
      const int n = n0 + wn + j * 16 + (lane & 15);
#pragma unroll
      for (int r = 0; r < 4; ++r)
        Hp[(size_t)(mb + r) * NC + n] = f2bf(acc[i][j][r] * rinv[r]);
    }
  }
}

// ---------------------------------------------------------------------------
// Output projection + residual: out[o,t] = Wp·H^T + bp[o] + x[o,t], fp32.
// flat grid (128, 1, B): XCD-grouped so one H row-stripe serves 4 m0 chunks.
// Depth-4 prefetch (80 KB LDS): same grid-512 / 2-blocks-per-CU reasoning.
// ---------------------------------------------------------------------------
__global__ __launch_bounds__(256, 2) void k_out(const short* __restrict__ W,
                                                const short* __restrict__ H,
                                                const float* __restrict__ bias,
                                                const float* __restrict__ x,
                                                float* __restrict__ out) {
  GEMM_LDS5;
  const int b = blockIdx.z;
  int row, chunk;
  xcd_rowchunk((int)blockIdx.x, NT / 128, row, chunk);
  const int n0 = row * 128;    // H row-stripe (B operand)
  const int m0 = chunk * 128;  // Wp row chunk
  ACC_INIT;
  gemm_tile<5>(W, NC, H + (size_t)b * NT * NC, NC, m0, n0, NC / 32, acc, lds);
  EPI_IDX;
#pragma unroll
  for (int j = 0; j < 4; ++j) {
    const int n = n0 + wn + j * 16 + (lane & 15);
#pragma unroll
    for (int i = 0; i < 4; ++i) {
      const int mb = m0 + wm + i * 16 + ((lane >> 4) * 4);
#pragma unroll
      for (int r = 0; r < 4; ++r) {
        const int m = mb + r;
        const size_t idx = ((size_t)b * NC + m) * NT + n;
        out[idx] = acc[i][j][r] + bias[m] + x[idx];
      }
    }
  }
}

// ---------------------------------------------------------------------------
extern "C" void kernel_launch(void* const* d_in, const int* in_sizes, int n_in,
                              void* d_out, int out_size, void* d_ws, size_t ws_size,
                              hipStream_t stream) {
  (void)in_sizes; (void)n_in; (void)out_size; (void)ws_size;
  const float* x  = (const float*)d_in[0];
  const float* Wq = (const float*)d_in[1];
  const float* bq = (const float*)d_in[2];
  const float* Wk = (const float*)d_in[3];
  const float* bk = (const float*)d_in[4];
  const float* Wv = (const float*)d_in[5];
  const float* bv = (const float*)d_in[6];
  const float* Wp = (const float*)d_in[7];
  const float* bp = (const float*)d_in[8];
  float* out = (float*)d_out;

  char* ws = (char*)d_ws;
  size_t off = 0;
  auto alloc = [&](size_t bytes) { char* p = ws + off; off += bytes; return p; };
  short* xT  = (short*)alloc((size_t)NB * NT * NC * 2);
  short* Qb  = (short*)alloc((size_t)NB * NT * NC * 2);
  short* Kb  = (short*)alloc((size_t)NB * NT * NC * 2);
  short* VTb = (short*)alloc((size_t)NB * NC * NT * 2);
  short* Hb  = (short*)alloc((size_t)NB * NT * NC * 2);
  short* Wqb = (short*)alloc((size_t)NC * NC * 2);
  short* Wkb = (short*)alloc((size_t)NC * NC * 2);
  short* Wvb = (short*)alloc((size_t)NC * NC * 2);
  short* Wpb = (short*)alloc((size_t)NC * NC * 2);
  float* Lr  = (float*)alloc((size_t)NB * NT * 4);
  short* Pb  = (short*)alloc((size_t)NB * NTILE * 16384 * 2);  // 69 MB packed

  hipMemsetAsync(Lr, 0, (size_t)NB * NT * 4, stream);

  const dim3 blk(256);
  k_wcvt<<<dim3(NC * NC / 1024, 4), blk, 0, stream>>>(Wq, Wk, Wv, Wp, Wqb, Wkb, Wvb, Wpb);

  k_transpose<<<dim3(NT / 32, NC / 32, NB), blk, 0, stream>>>(x, xT);

  k_qkv<<<dim3(128, 3, NB), blk, 0, stream>>>(xT, Wqb, bq, Wkb, bk, Wvb, bv, Qb, Kb, VTb);

  k_scores<<<dim3(NTILE, 1, NB), blk, 0, stream>>>(Qb, Kb, Pb, Lr);
  k_pv<<<dim3(128, 1, NB), blk, 0, stream>>>(Pb, VTb, Lr, Hb);
  k_out<<<dim3(128, 1, NB), blk, 0, stream>>>(Wpb, Hb, bp, x, out);
}

// Round 4
// 273.014 us; speedup vs baseline: 1.4937x; 1.4937x over previous
//
#include <hip/hip_runtime.h>

#define NB 4
#define NC 512
#define NT 4096
#define NTILE 528   // 32*33/2 triangular 128x128 tiles per batch

typedef __attribute__((ext_vector_type(4))) float f32x4;
typedef __attribute__((ext_vector_type(8))) short short8;

typedef const __attribute__((address_space(1))) unsigned int* gp1_t;
typedef __attribute__((address_space(3))) unsigned int* lp3_t;

__device__ __forceinline__ void gload16(const short* g, short* l) {
  // async global->LDS, 16B/lane; LDS dest = wave-uniform base + lane*16
  __builtin_amdgcn_global_load_lds((gp1_t)g, (lp3_t)l, 16, 0, 0);
}

// Raw barrier / waitcnt with memory clobbers: keeps the compiler from
// draining vmcnt(0) at every barrier. Each wave issues 4 DMAs per k-step;
// vmcnt(4*D) = the oldest step's 4 have landed (D = steps still in flight).
// ROUND-3 LESSON: depth-1 (NBUF=2) is catastrophic (k_qkv 50->152 us) --
// the promised 5-block residency never materialized (occ 31% ~= 2.5 blk/CU)
// and every kstep ate a full DMA round-trip. Keep depth >= 2 always.
#define BARRIER()  asm volatile("s_barrier" ::: "memory")
#define WAITVM0()  asm volatile("s_waitcnt vmcnt(0)" ::: "memory")
#define WAITVM4()  asm volatile("s_waitcnt vmcnt(4)" ::: "memory")
#define WAITVM8()  asm volatile("s_waitcnt vmcnt(8)" ::: "memory")
#define WAITVM12() asm volatile("s_waitcnt vmcnt(12)" ::: "memory")
#define WAITVM16() asm volatile("s_waitcnt vmcnt(16)" ::: "memory")

__device__ __forceinline__ short f2bf(float f) {
  union { float f; unsigned u; } v; v.f = f;
  unsigned r = v.u + 0x7fffu + ((v.u >> 16) & 1u);
  return (short)(r >> 16);
}
__device__ __forceinline__ float bf2f(short s) {
  union { unsigned u; float f; } v; v.u = ((unsigned)(unsigned short)s) << 16;
  return v.f;
}

// ---------------------------------------------------------------------------
// LDS XOR swizzle (T2): buffers are 64 rows x 32 shorts (64 B rows). Unswizzled
// fragment reads put a quarter-wave's 16 lanes (16 different rows, same 16B
// column-group) on 2 four-bank slots -> 8-way conflict. Store column-group
// cg at cg ^ s(row), s(row) = (row>>1)&3. With global_load_lds the LDS dest
// stays linear; swizzle via per-lane GLOBAL source column (rule 21) + read
// column. Both collapse to per-thread constants. Verified round 2:
// SQ_LDS_BANK_CONFLICT 4.33M -> 0.
// ---------------------------------------------------------------------------
#define SCOL_SWZ(lane) ((((lane) & 3) ^ (((lane) >> 3) & 3)) * 8)
#define FKO_SWZ(lane)  (((((lane) >> 4) ^ (((lane) >> 1) & 3)) & 3) * 8)

// ---------------------------------------------------------------------------
// Multi-buffered NT-GEMM core, prefetch depth NBUF-1: D[m,n] += sum_k A[m,k]*B[n,k]
// 128x128 tile, BK=32, 4 waves, 4x4 of 16x16x32 bf16 MFMAs per wave.
// lds: NBUF*8192 shorts, buffer b at lds + b*8192 (A 4096 + B 4096).
// NBUF=3 (48 KB): depth-2, 3 blocks/CU -- the proven config (round 2).
// NBUF=5 (80 KB): grid-512 kernels (2 blocks/CU regardless), deep prefetch.
// ---------------------------------------------------------------------------
template <int NBUF>
__device__ __forceinline__ void gemm_tile(const short* __restrict__ A, int lda,
                                          const short* __restrict__ Bg, int ldb,
                                          int m0, int n0, int ksteps,
                                          f32x4 (&acc)[4][4], short* lds) {
  const int tid  = threadIdx.x;
  const int lane = tid & 63;
  const int wv   = tid >> 6;
  const int wm = (wv >> 1) * 64;
  const int wn = (wv & 1) * 64;
  const int srow = wv * 16 + (lane >> 2);   // staging row, 0..63 (+64 issue 1)
  const int scol = SCOL_SWZ(lane);          // swizzled staging col (shorts)
  const int fm  = lane & 15;                // fragment row
  const int fko = FKO_SWZ(lane);            // swizzled fragment k offset

  const short* Ap0 = A  + (size_t)(m0 + srow) * lda + scol;
  const short* Ap1 = Ap0 + (size_t)64 * lda;
  const short* Bp0 = Bg + (size_t)(n0 + srow) * ldb + scol;
  const short* Bp1 = Bp0 + (size_t)64 * ldb;

  auto issue = [&](int kt) {
    short* base = lds + (kt % NBUF) * 8192;
    const int k0 = kt * 32;
    gload16(Ap0 + k0, base + wv * 512);
    gload16(Ap1 + k0, base + 2048 + wv * 512);
    gload16(Bp0 + k0, base + 4096 + wv * 512);
    gload16(Bp1 + k0, base + 6144 + wv * 512);
  };

  issue(0);
#pragma unroll
  for (int p = 1; p < NBUF - 1; ++p)
    if (p < ksteps) issue(p);

  for (int kt = 0; kt < ksteps; ++kt) {
    const short* As = lds + (kt % NBUF) * 8192;
    const short* Bs = As + 4096;
    if (kt) BARRIER();                      // prior readers of reused buf done
    if constexpr (NBUF == 5) {
      if (kt + 4 < ksteps)      { issue(kt + 4); WAITVM16(); }
      else if (kt + 3 < ksteps) { WAITVM12(); }
      else if (kt + 2 < ksteps) { WAITVM8(); }
      else if (kt + 1 < ksteps) { WAITVM4(); }
      else                      { WAITVM0(); }
    } else {  // NBUF == 3, depth-2
      if (kt + 2 < ksteps)      { issue(kt + 2); WAITVM8(); }
      else if (kt + 1 < ksteps) { WAITVM4(); }
      else                      { WAITVM0(); }
    }
    BARRIER();                              // all waves' step-kt DMAs landed
    short8 af[4], bfr[4];
#pragma unroll
    for (int i = 0; i < 4; ++i)
      af[i] = *(const short8*)(As + (wm + i * 16 + fm) * 32 + fko);
#pragma unroll
    for (int j = 0; j < 4; ++j)
      bfr[j] = *(const short8*)(Bs + (wn + j * 16 + fm) * 32 + fko);
#pragma unroll
    for (int i = 0; i < 4; ++i)
#pragma unroll
      for (int j = 0; j < 4; ++j)
        acc[i][j] = __builtin_amdgcn_mfma_f32_16x16x32_bf16(af[i], bfr[j], acc[i][j], 0, 0, 0);
  }
}

#define ACC_INIT                                  \
  f32x4 acc[4][4];                                \
  {                                               \
    const f32x4 z = {0.f, 0.f, 0.f, 0.f};         \
    for (int i = 0; i < 4; ++i)                   \
      for (int j = 0; j < 4; ++j) acc[i][j] = z;  \
  }

#define EPI_IDX                                   \
  const int lane = threadIdx.x & 63;              \
  const int wave = threadIdx.x >> 6;              \
  const int wm = (wave >> 1) * 64;                \
  const int wn = (wave & 1) * 64;

#define GEMM_LDS3 __shared__ short lds[24576];    // 3 bufs, 48 KB -> 3 blocks/CU
#define GEMM_LDS5 __shared__ short lds[40960];    // 5 bufs, 80 KB

// ---------------------------------------------------------------------------
// XCD-locality swizzle for flat grids of (row-stripe, 4 col-chunks):
// dispatch round-robins blockIdx.x%8 across XCDs; decode so each XCD sees 4
// consecutive col-chunks of the same row-stripe. rows descend (long first).
// ---------------------------------------------------------------------------
__device__ __forceinline__ void xcd_rowchunk(int x, int nrows, int& row, int& chunk) {
  const int xcd  = x & 7;
  const int slot = x >> 3;
  row   = nrows - 1 - (xcd + 8 * (slot >> 2));
  chunk = slot & 3;
}

// ---------------------------------------------------------------------------
// Work-balanced row map for k_pv (triangular: ksteps = 4*(bm+1)).
// Each XCD x owns rows {31-x, 23-x, 8+x, x}; reversing order for z>=2 pairs
// long rows with short on the same CU -> every CU = 132 ksteps exactly.
// (Round-2 verified: k_pv dropped out of the top-5 dispatches.)
// ---------------------------------------------------------------------------
__device__ __forceinline__ void pv_rowchunk(int x, int z, int& bm, int& chunk) {
  const int xcd  = x & 7;
  const int slot = x >> 3;           // 0..15
  int ridx = slot >> 2;              // 0..3
  if (z >= 2) ridx = 3 - ridx;
  bm = (ridx == 0) ? (31 - xcd)
     : (ridx == 1) ? (23 - xcd)
     : (ridx == 2) ? (8 + xcd)
                   : xcd;
  chunk = slot & 3;
}

// ---------------------------------------------------------------------------
// x [B,C,T] f32 -> xT [B,T,C] bf16 (tiled transpose through LDS)
// ---------------------------------------------------------------------------
__global__ __launch_bounds__(256) void k_transpose(const float* __restrict__ x,
                                                   short* __restrict__ xT) {
  __shared__ float tile[32][33];
  const int b  = blockIdx.z;
  const int t0 = blockIdx.x * 32;
  const int c0 = blockIdx.y * 32;
  const int tx = threadIdx.x & 31;
  const int ty = threadIdx.x >> 5;
  const float* xp = x + ((size_t)b * NC + c0) * NT + t0;
#pragma unroll
  for (int i = 0; i < 32; i += 8)
    tile[ty + i][tx] = xp[(size_t)(ty + i) * NT + tx];
  __syncthreads();
  short* op = xT + ((size_t)b * NT + t0) * NC + c0;
#pragma unroll
  for (int i = 0; i < 32; i += 8)
    op[(size_t)(ty + i) * NC + tx] = f2bf(tile[tx][ty + i]);
}

// f32 -> bf16 conversion of all 4 weight matrices in one launch
__global__ __launch_bounds__(256) void k_wcvt(const float* __restrict__ s0, const float* __restrict__ s1,
                                              const float* __restrict__ s2, const float* __restrict__ s3,
                                              short* __restrict__ d0, short* __restrict__ d1,
                                              short* __restrict__ d2, short* __restrict__ d3) {
  const float* s; short* d;
  switch (blockIdx.y) {
    case 0: s = s0; d = d0; break;
    case 1: s = s1; d = d1; break;
    case 2: s = s2; d = d2; break;
    default: s = s3; d = d3; break;
  }
  const int i = (blockIdx.x * 256 + threadIdx.x) * 4;
  const float4 v = *(const float4*)(s + i);
  short4 o;
  o.x = f2bf(v.x); o.y = f2bf(v.y); o.z = f2bf(v.z); o.w = f2bf(v.w);
  *(short4*)(d + i) = o;
}

// ---------------------------------------------------------------------------
// Fused Q/K/V projections, one launch. blockIdx.y selects:
//   y=0: Q[t,o] = xT·Wq^T + bq   -> bf16 [T,C]
//   y=1: K[t,o] = xT·Wk^T + bk   -> bf16 [T,C]
//   y=2: VT[o,t] = Wv·xT^T + bv  -> bf16 [C,T]
// NBUF=3 / 48 KB: the round-2-proven config (~50 us).
// ---------------------------------------------------------------------------
__global__ __launch_bounds__(256, 3) void k_qkv(const short* __restrict__ xT,
                                                const short* __restrict__ Wq,
                                                const float* __restrict__ bq,
                                                const short* __restrict__ Wk,
                                                const float* __restrict__ bk,
                                                const short* __restrict__ Wv,
                                                const float* __restrict__ bv,
                                                short* __restrict__ Q,
                                                short* __restrict__ K,
                                                short* __restrict__ VT) {
  GEMM_LDS3;
  const int b = blockIdx.z;
  const int y = blockIdx.y;
  int row, chunk;
  xcd_rowchunk((int)blockIdx.x, NT / 128, row, chunk);
  const short* Xb = xT + (size_t)b * NT * NC;
  ACC_INIT;
  if (y < 2) {
    const short* W = (y == 0) ? Wq : Wk;
    const float* bias = (y == 0) ? bq : bk;
    short* O = ((y == 0) ? Q : K) + (size_t)b * NT * NC;
    const int m0 = row * 128;
    const int n0 = chunk * 128;
    gemm_tile<3>(Xb, NC, W, NC, m0, n0, NC / 32, acc, lds);
    EPI_IDX;
#pragma unroll
    for (int j = 0; j < 4; ++j) {
      const int n = n0 + wn + j * 16 + (lane & 15);
      const float bv_ = bias[n];
#pragma unroll
      for (int i = 0; i < 4; ++i) {
        const int mb = m0 + wm + i * 16 + ((lane >> 4) * 4);
#pragma unroll
        for (int r = 0; r < 4; ++r)
          O[(size_t)(mb + r) * NC + n] = f2bf(acc[i][j][r] + bv_);
      }
    }
  } else {
    const int n0 = row * 128;    // xT row-stripe (B operand)
    const int m0 = chunk * 128;  // Wv row chunk
    gemm_tile<3>(Wv, NC, Xb, NC, m0, n0, NC / 32, acc, lds);
    EPI_IDX;
    short* O = VT + (size_t)b * NC * NT;
#pragma unroll
    for (int j = 0; j < 4; ++j) {
      const int n = n0 + wn + j * 16 + (lane & 15);
#pragma unroll
      for (int i = 0; i < 4; ++i) {
        const int mb = m0 + wm + i * 16 + ((lane >> 4) * 4);
#pragma unroll
        for (int r = 0; r < 4; ++r)
          O[(size_t)(mb + r) * NT + n] = f2bf(acc[i][j][r] + bv[mb + r]);
      }
    }
  }
}

// ---------------------------------------------------------------------------
// Scores + softmax numerator into TRIANGULAR-PACKED tile layout.
// XCD-locality: 8x8-tile supertile decomposition; block x -> (xcd=x&7,
// slot=x>>3) gives each XCD a contiguous 66-tile range (~2 MB working set).
// P = exp(scale*q.k) for s<=t else 0, contiguous 128x128 bf16 tile.
// NBUF=3 / 48 KB: round-2-proven. Epilogue VALU diet kept from round 3:
// exp2f with folded scale*log2e constant + paired v_cvt_pk_bf16_f32 (RNE,
// identical rounding to manual f2bf).
// ---------------------------------------------------------------------------
__global__ __launch_bounds__(256, 3) void k_scores(const short* __restrict__ Q,
                                                   const short* __restrict__ K,
                                                   short* __restrict__ P,
                                                   float* __restrict__ Lrow) {
  // supertile-ordered position, contiguous per XCD
  const int p = (((int)blockIdx.x & 7) * 66) + ((int)blockIdx.x >> 3);
  int bm = 0, bn = 0;
  {
    int base = 0;
    for (int sr = 0; sr < 4; ++sr) {
      bool done = false;
      for (int sc = 0; sc <= sr; ++sc) {
        const int sz = (sc == sr) ? 36 : 64;
        if (p < base + sz) {
          const int q = p - base;
          int i, j;
          if (sc == sr) {
            i = 0;
            while ((i + 1) * (i + 2) / 2 <= q) ++i;
            j = q - i * (i + 1) / 2;
          } else { i = q >> 3; j = q & 7; }
          bm = sr * 8 + i; bn = sc * 8 + j;
          done = true; break;
        }
        base += sz;
      }
      if (done) break;
    }
  }
  GEMM_LDS3;
  const int b  = blockIdx.z;
  const int m0 = bm * 128;
  const int n0 = bn * 128;
  ACC_INIT;
  gemm_tile<3>(Q + (size_t)b * NT * NC, NC, K + (size_t)b * NT * NC, NC,
               m0, n0, NC / 32, acc, lds);
  EPI_IDX;
  const float kls = 0.06376070265f;          // 512^-0.5 * log2(e)
  const int idx = bm * (bm + 1) / 2 + bn;    // storage order unchanged
  short* Tp = P + ((size_t)b * NTILE + (size_t)idx) * 16384;
  float* Lp = Lrow + (size_t)b * NT;
  float psum[4][4];
#pragma unroll
  for (int i = 0; i < 4; ++i)
#pragma unroll
    for (int r = 0; r < 4; ++r) psum[i][r] = 0.f;

  if (bn < bm) {
    // interior: causal mask always true -- branchless, packed bf16 convert
#pragma unroll
    for (int j = 0; j < 4; ++j) {
      const int ln = wn + j * 16 + (lane & 15);
#pragma unroll
      for (int i = 0; i < 4; ++i) {
        const int lmb = wm + i * 16 + ((lane >> 4) * 4);
        const float e0 = exp2f(acc[i][j][0] * kls);
        const float e1 = exp2f(acc[i][j][1] * kls);
        const float e2 = exp2f(acc[i][j][2] * kls);
        const float e3 = exp2f(acc[i][j][3] * kls);
        unsigned pk01, pk23;
        asm("v_cvt_pk_bf16_f32 %0, %1, %2" : "=v"(pk01) : "v"(e0), "v"(e1));
        asm("v_cvt_pk_bf16_f32 %0, %1, %2" : "=v"(pk23) : "v"(e2), "v"(e3));
        Tp[(lmb + 0) * 128 + ln] = (short)(pk01 & 0xffffu);
        Tp[(lmb + 1) * 128 + ln] = (short)(pk01 >> 16);
        Tp[(lmb + 2) * 128 + ln] = (short)(pk23 & 0xffffu);
        Tp[(lmb + 3) * 128 + ln] = (short)(pk23 >> 16);
        // L accumulates exactly the rounded values P stores
        union { unsigned u; float f; } c0, c1, c2, c3;
        c0.u = pk01 << 16; c1.u = pk01 & 0xffff0000u;
        c2.u = pk23 << 16; c3.u = pk23 & 0xffff0000u;
        psum[i][0] += c0.f; psum[i][1] += c1.f;
        psum[i][2] += c2.f; psum[i][3] += c3.f;
      }
    }
  } else {
    // diagonal tile: evaluate mask per element
#pragma unroll
    for (int j = 0; j < 4; ++j) {
      const int ln = wn + j * 16 + (lane & 15);
      const int n  = n0 + ln;
#pragma unroll
      for (int i = 0; i < 4; ++i) {
        const int lmb = wm + i * 16 + ((lane >> 4) * 4);
#pragma unroll
        for (int r = 0; r < 4; ++r) {
          const int m = m0 + lmb + r;
          float pr = 0.f;
          short pb = 0;
          if (n <= m) {
            pb = f2bf(exp2f(acc[i][j][r] * kls));
            pr = bf2f(pb);
          }
          Tp[(lmb + r) * 128 + ln] = pb;
          psum[i][r] += pr;
        }
      }
    }
  }
#pragma unroll
  for (int i = 0; i < 4; ++i)
#pragma unroll
    for (int r = 0; r < 4; ++r) {
      float v = psum[i][r];
      v += __shfl_xor(v, 1);
      v += __shfl_xor(v, 2);
      v += __shfl_xor(v, 4);
      v += __shfl_xor(v, 8);
      if ((lane & 15) == 0) {
        const int m = m0 + wm + i * 16 + ((lane >> 4) * 4) + r;
        atomicAdd(&Lp[m], v);
      }
    }
}

// ---------------------------------------------------------------------------
// PV: H[t,c] = (1/L[t]) * sum_{s<=t} P[t,s] * VT[c,s]  -> bf16 [T,C]
// flat grid (128, 1, B): XCD-grouped, work-balanced row map (see pv_rowchunk).
// Depth-4 prefetch (5 LDS buffers, 80 KB): 2 blocks/CU either way.
// ---------------------------------------------------------------------------
__global__ __launch_bounds__(256, 2) void k_pv(const short* __restrict__ P,
                                               const short* __restrict__ VT,
                                               const float* __restrict__ Lr,
                                               short* __restrict__ H) {
  GEMM_LDS5;
  const int b = blockIdx.z;
  int bm, chunk;
  pv_rowchunk((int)blockIdx.x, b, bm, chunk);
  const int m0 = bm * 128;
  const int n0 = chunk * 128;
  const int ksteps = (bm + 1) * 4;

  const short* Ptri = P + ((size_t)b * NTILE + (size_t)bm * (bm + 1) / 2) * 16384;
  const short* Bg   = VT + (size_t)b * NC * NT;

  ACC_INIT;
  const int tid  = threadIdx.x;
  const int lane = tid & 63;
  const int wv   = tid >> 6;
  const int wm = (wv >> 1) * 64;
  const int wn = (wv & 1) * 64;
  const int srow = wv * 16 + (lane >> 2);
  const int scol = SCOL_SWZ(lane);
  const int fm  = lane & 15;
  const int fko = FKO_SWZ(lane);

  const short* Bp0 = Bg + (size_t)(n0 + srow) * NT + scol;
  const short* Bp1 = Bp0 + (size_t)64 * NT;

  auto issue = [&](int kt) {
    short* base = lds + (kt % 5) * 8192;
    const short* At = Ptri + (size_t)(kt >> 2) * 16384 + (kt & 3) * 32;
    const short* Ap0 = At + srow * 128 + scol;
    const int k0 = kt * 32;
    gload16(Ap0, base + wv * 512);
    gload16(Ap0 + 64 * 128, base + 2048 + wv * 512);
    gload16(Bp0 + k0, base + 4096 + wv * 512);
    gload16(Bp1 + k0, base + 6144 + wv * 512);
  };

  issue(0);
#pragma unroll
  for (int p = 1; p < 4; ++p)
    if (p < ksteps) issue(p);
  for (int kt = 0; kt < ksteps; ++kt) {
    const short* As = lds + (kt % 5) * 8192;
    const short* Bs = As + 4096;
    if (kt) BARRIER();
    if (kt + 4 < ksteps)      { issue(kt + 4); WAITVM16(); }
    else if (kt + 3 < ksteps) { WAITVM12(); }
    else if (kt + 2 < ksteps) { WAITVM8(); }
    else if (kt + 1 < ksteps) { WAITVM4(); }
    else                      { WAITVM0(); }
    BARRIER();
    short8 af[4], bfr[4];
#pragma unroll
    for (int i = 0; i < 4; ++i)
      af[i] = *(const short8*)(As + (wm + i * 16 + fm) * 32 + fko);
#pragma unroll
    for (int j = 0; j < 4; ++j)
      bfr[j] = *(const short8*)(Bs + (wn + j * 16 + fm) * 32 + fko);
#pragma unroll
    for (int i = 0; i < 4; ++i)
#pragma unroll
      for (int j = 0; j < 4; ++j)
        acc[i][j] = __builtin_amdgcn_mfma_f32_16x16x32_bf16(af[i], bfr[j], acc[i][j], 0, 0, 0);
  }

  const float* L = Lr + (size_t)b * NT;
  short* Hp = H + (size_t)b * NT * NC;
#pragma unroll
  for (int i = 0; i < 4; ++i) {
    const int mb = m0 + wm + i * 16 + ((lane >> 4) * 4);
    float rinv[4];
#pragma unroll
    for (int r = 0; r < 4; ++r) rinv[r] = 1.f / L[mb + r];
#pragma unroll
    for (int j = 0; j < 4; ++j) {
      const int n = n0 + wn + j * 16 + (lane & 15);
#pragma unroll
      for (int r = 0; r < 4; ++r)
        Hp[(size_t)(mb + r) * NC + n] = f2bf(acc[i][j][r] * rinv[r]);
    }
  }
}

// ---------------------------------------------------------------------------
// Output projection + residual: out[o,t] = Wp·H^T + bp[o] + x[o,t], fp32.
// flat grid (128, 1, B): XCD-grouped so one H row-stripe serves 4 m0 chunks.
// Depth-4 prefetch (80 KB LDS): same grid-512 / 2-blocks-per-CU reasoning.
// ---------------------------------------------------------------------------
__global__ __launch_bounds__(256, 2) void k_out(const short* __restrict__ W,
                                                const short* __restrict__ H,
                                                const float* __restrict__ bias,
                                                const float* __restrict__ x,
                                                float* __restrict__ out) {
  GEMM_LDS5;
  const int b = blockIdx.z;
  int row, chunk;
  xcd_rowchunk((int)blockIdx.x, NT / 128, row, chunk);
  const int n0 = row * 128;    // H row-stripe (B operand)
  const int m0 = chunk * 128;  // Wp row chunk
  ACC_INIT;
  gemm_tile<5>(W, NC, H + (size_t)b * NT * NC, NC, m0, n0, NC / 32, acc, lds);
  EPI_IDX;
#pragma unroll
  for (int j = 0; j < 4; ++j) {
    const int n = n0 + wn + j * 16 + (lane & 15);
#pragma unroll
    for (int i = 0; i < 4; ++i) {
      const int mb = m0 + wm + i * 16 + ((lane >> 4) * 4);
#pragma unroll
      for (int r = 0; r < 4; ++r) {
        const int m = mb + r;
        const size_t idx = ((size_t)b * NC + m) * NT + n;
        out[idx] = acc[i][j][r] + bias[m] + x[idx];
      }
    }
  }
}

// ---------------------------------------------------------------------------
extern "C" void kernel_launch(void* const* d_in, const int* in_sizes, int n_in,
                              void* d_out, int out_size, void* d_ws, size_t ws_size,
                              hipStream_t stream) {
  (void)in_sizes; (void)n_in; (void)out_size; (void)ws_size;
  const float* x  = (const float*)d_in[0];
  const float* Wq = (const float*)d_in[1];
  const float* bq = (const float*)d_in[2];
  const float* Wk = (const float*)d_in[3];
  const float* bk = (const float*)d_in[4];
  const float* Wv = (const float*)d_in[5];
  const float* bv = (const float*)d_in[6];
  const float* Wp = (const float*)d_in[7];
  const float* bp = (const float*)d_in[8];
  float* out = (float*)d_out;

  char* ws = (char*)d_ws;
  size_t off = 0;
  auto alloc = [&](size_t bytes) { char* p = ws + off; off += bytes; return p; };
  short* xT  = (short*)alloc((size_t)NB * NT * NC * 2);
  short* Qb  = (short*)alloc((size_t)NB * NT * NC * 2);
  short* Kb  = (short*)alloc((size_t)NB * NT * NC * 2);
  short* VTb = (short*)alloc((size_t)NB * NC * NT * 2);
  short* Hb  = (short*)alloc((size_t)NB * NT * NC * 2);
  short* Wqb = (short*)alloc((size_t)NC * NC * 2);
  short* Wkb = (short*)alloc((size_t)NC * NC * 2);
  short* Wvb = (short*)alloc((size_t)NC * NC * 2);
  short* Wpb = (short*)alloc((size_t)NC * NC * 2);
  float* Lr  = (float*)alloc((size_t)NB * NT * 4);
  short* Pb  = (short*)alloc((size_t)NB * NTILE * 16384 * 2);  // 69 MB packed

  hipMemsetAsync(Lr, 0, (size_t)NB * NT * 4, stream);

  const dim3 blk(256);
  k_wcvt<<<dim3(NC * NC / 1024, 4), blk, 0, stream>>>(Wq, Wk, Wv, Wp, Wqb, Wkb, Wvb, Wpb);

  k_transpose<<<dim3(NT / 32, NC / 32, NB), blk, 0, stream>>>(x, xT);

  k_qkv<<<dim3(128, 3, NB), blk, 0, stream>>>(xT, Wqb, bq, Wkb, bk, Wvb, bv, Qb, Kb, VTb);

  k_scores<<<dim3(NTILE, 1, NB), blk, 0, stream>>>(Qb, Kb, Pb, Lr);
  k_pv<<<dim3(128, 1, NB), blk, 0, stream>>>(Pb, VTb, Lr, Hb);
  k_out<<<dim3(128, 1, NB), blk, 0, stream>>>(Wpb, Hb, bp, x, out);
}